// Round 7
// baseline (55.281 us; speedup 1.0000x reference)
//
#include <hip/hip_runtime.h>

// Problem constants (match reference)
#define LDIM 128
#define FDIM 64
#define NVALS 129      // counts range 0..128
#define NODE_MAX 1024  // id domain [0, 1024)
#define TBYTES (NVALS * FDIM * 4)   // 33024 B table
#define TV4    (NVALS * FDIM / 4)   // 2064 f32x4

typedef float f32x4 __attribute__((ext_vector_type(4)));

// ---------------------------------------------------------------------------
// Kernel 1: lookup table T[v][g] = relu(v*W1+b1)@W2 + b2.  33 blocks, 4 v each.
// feat(pos) = T[self_cnt] + T[cross_cnt]; masked pos -> T[0]+T[0] == encode(0,0).
// ---------------------------------------------------------------------------
__global__ __launch_bounds__(256) void build_table_kernel(
    const float* __restrict__ W1, const float* __restrict__ b1,
    const float* __restrict__ W2, const float* __restrict__ b2,
    float* __restrict__ T)
{
    const int t  = threadIdx.x;
    const int vi = t >> 6, g = t & 63;
    const int v  = blockIdx.x * 4 + vi;

    __shared__ float h[4][FDIM];
    h[vi][g] = fmaxf((float)v * W1[g] + b1[g], 0.0f);
    __syncthreads();

    if (v < NVALS) {
        float acc = b2[g];
#pragma unroll
        for (int f = 0; f < FDIM; ++f)
            acc = fmaf(h[vi][f], W2[f * FDIM + g], acc);  // W2[f][g]
        T[v * FDIM + g] = acc;
    }
}

// ---------------------------------------------------------------------------
// Kernel 2 (fused, LDS-fed stores): one block per batch row, 256 threads.
//   LDS union: `tbl` region is the 2x1024-int histogram during Phase B,
//   then overwritten with the 33KB table for Phase C. ids + packed counts
//   live outside the union. ~35KB/block -> 4 blocks/CU (16 waves).
//   Phase C reads operands via ds_read_b128 (separate LDS pipe), so the
//   VMEM path issues ONLY stores — same structure as fillBuffer (7 TB/s
//   at 10% occupancy). No dependent VMEM-gather chain in front of stores.
// ---------------------------------------------------------------------------
__global__ __launch_bounds__(256) void encode_rows_kernel(
    const int* __restrict__ src, const int* __restrict__ dst,
    const float* __restrict__ T,
    float* __restrict__ out_src, float* __restrict__ out_dst)
{
    const int b = blockIdx.x;
    const int t = threadIdx.x;

    __shared__ __align__(16) char tbl[TBYTES];  // hist (8KB) then table (33KB)
    __shared__ int ids[2 * LDIM];               // src ids | dst ids
    __shared__ int cnt[2 * LDIM];               // packed a | b<<8 per position

    int* hist = (int*)tbl;                      // histS = hist[0..1024), histD = [1024..2048)

    // Phase A: issue id load early; zero histograms (2 int4 each).
    const int myId = (t < LDIM) ? src[(size_t)b * LDIM + t]
                                : dst[(size_t)b * LDIM + (t - LDIM)];
    ((int4*)hist)[t]       = make_int4(0, 0, 0, 0);
    ((int4*)hist)[t + 256] = make_int4(0, 0, 0, 0);
    ids[t] = myId;
    __syncthreads();

    // Phase B: histogram (order-independent -> deterministic), then counts.
    atomicAdd(&hist[((t >> 7) << 10) + myId], 1);   // t<128 -> histS, else histD
    __syncthreads();

    {
        const int self_base  = (t >> 7) << 10;       // own side's hist
        const int cross_base = 1024 - self_base;     // other side's hist
        int a = hist[self_base + myId];
        int c = hist[cross_base + myId];
        if (myId == 0) { a = 0; c = 0; }
        cnt[t] = a | (c << 8);
    }
    __syncthreads();                                 // hist region now free

    // Phase A2: stage the 33KB table into LDS (overwrites hist region).
    {
        f32x4*       dstv = (f32x4*)tbl;
        const f32x4* srcv = (const f32x4*)T;
        for (int i = t; i < TV4; i += 256)
            dstv[i] = srcv[i];
    }
    __syncthreads();

    // Phase C: 2048 f32x4 per side; operands from LDS, VMEM = stores only.
    const f32x4* __restrict__ T4 = (const f32x4*)tbl;   // T4[v*16 + ch]
    f32x4* __restrict__ o4s = (f32x4*)out_src;
    f32x4* __restrict__ o4d = (f32x4*)out_dst;
    const size_t rowBase = (size_t)b * (LDIM * FDIM / 4);

#pragma unroll
    for (int k = 0; k < 8; ++k) {
        const int c   = t + k * 256;     // 0..2047
        const int pos = c >> 4;
        const int ch  = c & 15;

        const int qs = cnt[pos];
        o4s[rowBase + c] = T4[(qs & 255) * 16 + ch] + T4[(qs >> 8) * 16 + ch];

        const int qd = cnt[LDIM + pos];
        o4d[rowBase + c] = T4[(qd & 255) * 16 + ch] + T4[(qd >> 8) * 16 + ch];
    }
}

extern "C" void kernel_launch(void* const* d_in, const int* in_sizes, int n_in,
                              void* d_out, int out_size, void* d_ws, size_t ws_size,
                              hipStream_t stream)
{
    const int*   src = (const int*)d_in[0];    // int64 in ref -> int32 from harness
    const int*   dst = (const int*)d_in[1];
    const float* W1  = (const float*)d_in[2];  // [1,F]
    const float* b1  = (const float*)d_in[3];  // [F]
    const float* W2  = (const float*)d_in[4];  // [F,F]
    const float* b2  = (const float*)d_in[5];  // [F]

    float* out = (float*)d_out;                // [src_feat | dst_feat]
    float* T   = (float*)d_ws;                 // 129*64 f32 = 33 KB

    const int B = in_sizes[0] / LDIM;          // 4096
    const size_t half = (size_t)B * LDIM * FDIM;

    build_table_kernel<<<33, 256, 0, stream>>>(W1, b1, W2, b2, T);
    encode_rows_kernel<<<B, 256, 0, stream>>>(src, dst, T, out, out + half);
}

// Round 8
// 50.569 us; speedup vs baseline: 1.0932x; 1.0932x over previous
//
#include <hip/hip_runtime.h>

// Problem constants (match reference)
#define LDIM 128
#define FDIM 64
#define NVALS 129      // counts range 0..128
#define MAXSLOTS 64    // distinct count-values per block provably <= 61:
                       // occurrence-sets of distinct ids are disjoint ->
                       // sum of distinct counts <= 128 -> <= 15 nonzero values
                       // per category; 4 categories (srcSelf,srcCross,dstSelf,
                       // dstCross) + value 0 -> <= 61.

typedef float f32x4 __attribute__((ext_vector_type(4)));

// ---------------------------------------------------------------------------
// Single fused kernel: one block per batch row, 256 threads, ONE dispatch.
//   Phase A: load ids; zero hist (aliased into Tl's first 8KB); init slot map.
//   Phase B: LDS-histogram counts (order-independent -> deterministic);
//            mark present count-values; assign compact slots (slot order is
//            nondeterministic but Tl[slot(v)] == T[v] always -> output exact).
//   Phase T: compute Tl[s][g] = relu(v*W1+b1)@W2 + b2 for the <= 61 present
//            values only (4 values per round, typically 2 rounds). Weights are
//            tiny and L1/L2-hot; masked pos -> value 0 -> exact encode of (0,0).
//   Phase C: stream 2x128x64 f32 as plain f32x4 stores fed from LDS.
// LDS ~19.2 KB -> 8 blocks/CU (wave cap). No table round-trip, no 2nd launch.
// ---------------------------------------------------------------------------
__global__ __launch_bounds__(256) void fused_encode_kernel(
    const int* __restrict__ src, const int* __restrict__ dst,
    const float* __restrict__ W1, const float* __restrict__ b1,
    const float* __restrict__ W2, const float* __restrict__ b2,
    float* __restrict__ out_src, float* __restrict__ out_dst)
{
    const int b = blockIdx.x;
    const int t = threadIdx.x;

    __shared__ __align__(16) float Tl[MAXSLOTS * FDIM]; // 16 KB; first 8 KB = hist
    __shared__ float h[4][FDIM];                        // 1 KB staging
    __shared__ int slotOf[NVALS];                       // value -> slot
    __shared__ int marked[MAXSLOTS];                    // slot -> value
    __shared__ int cnt[2 * LDIM];                       // packed slot pair / pos
    __shared__ int nslots;

    int* hist = (int*)Tl;   // [0..1024) src-side, [1024..2048) dst-side

    // Phase A
    const int myId = (t < LDIM) ? src[(size_t)b * LDIM + t]
                                : dst[(size_t)b * LDIM + (t - LDIM)];
    ((int4*)hist)[t]       = make_int4(0, 0, 0, 0);
    ((int4*)hist)[t + 256] = make_int4(0, 0, 0, 0);
    if (t < NVALS) slotOf[t] = -1;
    if (t == 0) nslots = 0;
    __syncthreads();

    // Phase B: histogram
    atomicAdd(&hist[((t >> 7) << 10) + myId], 1);
    __syncthreads();

    int a, c;
    {
        const int self_base  = (t >> 7) << 10;      // own side's hist
        const int cross_base = 1024 - self_base;    // other side's hist
        a = hist[self_base + myId];
        c = hist[cross_base + myId];
        if (myId == 0) { a = 0; c = 0; }            // padding mask -> freq (0,0)
        slotOf[a] = -2;                             // mark present (idempotent)
        slotOf[c] = -2;
    }
    __syncthreads();

    // slot assignment (compact)
    if (t < NVALS && slotOf[t] == -2) {
        const int s = atomicAdd(&nslots, 1);
        slotOf[t] = s;
        marked[s] = t;
    }
    __syncthreads();

    cnt[t] = slotOf[a] | (slotOf[c] << 8);
    const int ns = nslots;                          // block-uniform

    // Phase T: per-block mini table over present values (hist region now dead;
    // ns >= 1 always, so the loop's barriers also cover the cnt[] writes).
    const int vi = t >> 6, g = t & 63;
    for (int s0 = 0; s0 < ns; s0 += 4) {
        const int s = s0 + vi;
        const bool act = (s < ns);
        float v = 0.0f;
        if (act) {
            v = (float)marked[s];
            h[vi][g] = fmaxf(v * W1[g] + b1[g], 0.0f);
        }
        __syncthreads();
        if (act) {
            float acc = b2[g];
#pragma unroll
            for (int f = 0; f < FDIM; ++f)
                acc = fmaf(h[vi][f], W2[f * FDIM + g], acc);  // W2[f][g]
            Tl[s * FDIM + g] = acc;
        }
        __syncthreads();
    }

    // Phase C: 2048 f32x4 per side; operands from LDS, VMEM issues stores only.
    const f32x4* __restrict__ T4 = (const f32x4*)Tl;    // T4[slot*16 + ch]
    f32x4* __restrict__ o4s = (f32x4*)out_src;
    f32x4* __restrict__ o4d = (f32x4*)out_dst;
    const size_t rowBase = (size_t)b * (LDIM * FDIM / 4);

#pragma unroll
    for (int k = 0; k < 8; ++k) {
        const int ci  = t + k * 256;    // 0..2047
        const int pos = ci >> 4;
        const int ch  = ci & 15;

        const int qs = cnt[pos];
        o4s[rowBase + ci] = T4[(qs & 255) * 16 + ch] + T4[((qs >> 8) & 255) * 16 + ch];

        const int qd = cnt[LDIM + pos];
        o4d[rowBase + ci] = T4[(qd & 255) * 16 + ch] + T4[((qd >> 8) & 255) * 16 + ch];
    }
}

extern "C" void kernel_launch(void* const* d_in, const int* in_sizes, int n_in,
                              void* d_out, int out_size, void* d_ws, size_t ws_size,
                              hipStream_t stream)
{
    const int*   src = (const int*)d_in[0];    // int64 in ref -> int32 from harness
    const int*   dst = (const int*)d_in[1];
    const float* W1  = (const float*)d_in[2];  // [1,F]
    const float* b1  = (const float*)d_in[3];  // [F]
    const float* W2  = (const float*)d_in[4];  // [F,F]
    const float* b2  = (const float*)d_in[5];  // [F]

    float* out = (float*)d_out;                // [src_feat | dst_feat]

    const int B = in_sizes[0] / LDIM;          // 4096
    const size_t half = (size_t)B * LDIM * FDIM;

    fused_encode_kernel<<<B, 256, 0, stream>>>(src, dst, W1, b1, W2, b2,
                                               out, out + half);
}